// Round 1
// baseline (255.455 us; speedup 1.0000x reference)
//
#include <hip/hip_runtime.h>
#include <math.h>

// PseudoGroupContrast loss, fp32 register-tiled version (round 0 baseline).
//
// Math (eps dropped inside logs; bias ~2e-4 << 5.9e-2 threshold):
//   f̂ = act/max(||act||,1e-12)  (queue_list arrives pre-normalized)
//   dot_q  = f̂·q̂,  dot_ef = f̂·êf
//   denom  = exp(dot_ef/T) + Σ_q exp(dot_q/T)           (375 queue rows)
//   per    = (126*log(denom) - (Σ_{q in label block} dot_q + dot_ef)/T)/126
//   out    = Σ_b mask_b * per_b / B

#define D        128
#define NQ       375
#define QS       125
#define MTILE    64
#define CHUNK    64
#define NCHUNKS  6          // 6*64 = 384 >= 375
#define FSTRIDE  132        // 128 + 4 floats pad: 16B-aligned rows, spread banks
#define INV_T    2.0f       // 1/TEMP

__global__ __launch_bounds__(256, 2) void pgc_kernel(
    const float* __restrict__ act,
    const float* __restrict__ ema,
    const float* __restrict__ plab,
    const float* __restrict__ mask,
    const float* __restrict__ queue,
    float* __restrict__ out,
    int B, float invB)
{
    __shared__ float f_lds[MTILE * FSTRIDE];   // raw activation tile
    __shared__ float q_lds[CHUNK * FSTRIDE];   // queue chunk
    __shared__ float s_invnf[MTILE];
    __shared__ float s_def[MTILE];             // dot(f_hat, ef_hat)
    __shared__ float s_mask[MTILE];
    __shared__ int   s_lab[MTILE];
    __shared__ float s_red[4];

    const int tid = threadIdx.x;
    const int tm  = tid >> 4;    // 0..15  (sample group)
    const int tr  = tid & 15;    // 0..15  (queue-row group)
    const long block_m0 = (long)blockIdx.x * MTILE;

    // ---- stage activation tile + per-row stats (4 lanes per row) ----
    {
        const int row = tid >> 2;        // 0..63
        const int seg = tid & 3;         // 0..3, 32 floats each
        const long grow = block_m0 + row;
        const bool valid = grow < (long)B;

        float4 av[8];
        float ssa = 0.f;
        const float* arow = act + grow * D + seg * 32;
        #pragma unroll
        for (int it = 0; it < 8; ++it) {
            float4 v = valid ? *(const float4*)(arow + it * 4)
                             : make_float4(0.f, 0.f, 0.f, 0.f);
            av[it] = v;
            ssa += v.x*v.x + v.y*v.y + v.z*v.z + v.w*v.w;
            *(float4*)&f_lds[row * FSTRIDE + seg * 32 + it * 4] = v;
        }
        float sse = 0.f, dae = 0.f;
        const float* erow = ema + grow * D + seg * 32;
        #pragma unroll
        for (int it = 0; it < 8; ++it) {
            float4 e = valid ? *(const float4*)(erow + it * 4)
                             : make_float4(0.f, 0.f, 0.f, 0.f);
            sse += e.x*e.x + e.y*e.y + e.z*e.z + e.w*e.w;
            dae += av[it].x*e.x + av[it].y*e.y + av[it].z*e.z + av[it].w*e.w;
        }
        // reduce the 4 lanes sharing this row
        ssa += __shfl_xor(ssa, 1); ssa += __shfl_xor(ssa, 2);
        sse += __shfl_xor(sse, 1); sse += __shfl_xor(sse, 2);
        dae += __shfl_xor(dae, 1); dae += __shfl_xor(dae, 2);

        const float inva = 1.0f / fmaxf(sqrtf(ssa), 1e-12f);
        const float inve = 1.0f / fmaxf(sqrtf(sse), 1e-12f);
        if (seg == 0) { s_invnf[row] = inva; s_def[row] = dae * inva * inve; }
        if (seg == 1) { s_mask[row] = valid ? mask[grow] : 0.f; }
        if (seg == 2) {
            int lb = 0;
            if (valid) {
                const float* p = plab + grow * 3;
                float p0 = p[0], p1 = p[1], p2 = p[2];
                float bst = p0;
                if (p1 > bst) { bst = p1; lb = 1; }   // first-max tie-break, matches argmax
                if (p2 > bst) { lb = 2; }
            }
            s_lab[row] = lb;
        }
    }

    float S1[4] = {0.f, 0.f, 0.f, 0.f};   // sum of exp(dot/T) over all queue rows
    float S2[4] = {0.f, 0.f, 0.f, 0.f};   // sum of dot over the label block

    for (int c = 0; c < NCHUNKS; ++c) {
        __syncthreads();
        // ---- stage queue chunk (fully coalesced) ----
        #pragma unroll
        for (int it = 0; it < 8; ++it) {
            int idx = it * 256 + tid;          // float4 index in 64x32 tile
            int row = idx >> 5;
            int c4  = idx & 31;
            int gr  = c * CHUNK + row;
            float4 v = make_float4(0.f, 0.f, 0.f, 0.f);
            if (gr < NQ) v = *(const float4*)(queue + (long)gr * D + c4 * 4);
            *(float4*)&q_lds[row * FSTRIDE + c4 * 4] = v;
        }
        __syncthreads();

        // ---- 4x4 register tile GEMM over K=128 ----
        float acc[4][4] = {};
        #pragma unroll 4
        for (int k4 = 0; k4 < 32; ++k4) {
            float4 fa[4], qb[4];
            #pragma unroll
            for (int i = 0; i < 4; ++i)
                fa[i] = *(const float4*)&f_lds[(i * 16 + tm) * FSTRIDE + k4 * 4];
            #pragma unroll
            for (int j = 0; j < 4; ++j)
                qb[j] = *(const float4*)&q_lds[(j * 16 + tr) * FSTRIDE + k4 * 4];
            #pragma unroll
            for (int i = 0; i < 4; ++i) {
                #pragma unroll
                for (int j = 0; j < 4; ++j) {
                    acc[i][j] += fa[i].x * qb[j].x + fa[i].y * qb[j].y
                               + fa[i].z * qb[j].z + fa[i].w * qb[j].w;
                }
            }
        }

        // ---- chunk epilogue: fold raw dots into S1/S2 ----
        #pragma unroll
        for (int i = 0; i < 4; ++i) {
            const int   m    = i * 16 + tm;
            const float inva = s_invnf[m];
            const int   lb   = s_lab[m];
            const int   lo   = lb * QS, hi = lb * QS + QS;
            #pragma unroll
            for (int j = 0; j < 4; ++j) {
                int gr = c * CHUNK + j * 16 + tr;
                if (gr < NQ) {
                    float dt = acc[i][j] * inva;
                    S1[i] += __expf(INV_T * dt);
                    if (gr >= lo && gr < hi) S2[i] += dt;
                }
            }
        }
    }

    // ---- reduce S1/S2 across the 16 tr lanes ----
    #pragma unroll
    for (int i = 0; i < 4; ++i) {
        #pragma unroll
        for (int w = 1; w <= 8; w <<= 1) {
            S1[i] += __shfl_xor(S1[i], w);
            S2[i] += __shfl_xor(S2[i], w);
        }
    }

    float contrib = 0.f;
    if (tr == 0) {
        #pragma unroll
        for (int i = 0; i < 4; ++i) {
            const int   m     = i * 16 + tm;
            const float defv  = s_def[m];
            const float lpos  = __expf(INV_T * defv);
            const float denom = lpos + S1[i];
            const float per   = (126.0f * __logf(denom)
                                 - INV_T * (S2[i] + defv)) * (1.0f / 126.0f);
            contrib += s_mask[m] * per;
        }
    }
    // full-wave reduce (non-tr0 lanes hold 0)
    #pragma unroll
    for (int w = 1; w <= 32; w <<= 1) contrib += __shfl_xor(contrib, w);

    const int wave = tid >> 6;
    if ((tid & 63) == 0) s_red[wave] = contrib;
    __syncthreads();
    if (tid == 0) {
        float t = s_red[0] + s_red[1] + s_red[2] + s_red[3];
        atomicAdd(out, t * invB);
    }
}

extern "C" void kernel_launch(void* const* d_in, const int* in_sizes, int n_in,
                              void* d_out, int out_size, void* d_ws, size_t ws_size,
                              hipStream_t stream)
{
    const float* act   = (const float*)d_in[0];
    const float* ema   = (const float*)d_in[1];
    const float* plab  = (const float*)d_in[2];
    const float* mask  = (const float*)d_in[3];
    const float* queue = (const float*)d_in[4];
    float* out = (float*)d_out;

    const int B = in_sizes[0] / D;

    hipMemsetAsync(out, 0, sizeof(float), stream);

    const int grid = (B + MTILE - 1) / MTILE;
    pgc_kernel<<<grid, 256, 0, stream>>>(act, ema, plab, mask, queue, out,
                                         B, 1.0f / (float)B);
}

// Round 3
// 122.962 us; speedup vs baseline: 2.0775x; 2.0775x over previous
//
#include <hip/hip_runtime.h>
#include <math.h>

// PseudoGroupContrast loss — bf16 MFMA version.
//
//   g = 2*f_hat stored bf16 -> MFMA acc = 2*dot directly
//   S1 = sum_q exp(2*dot)        (pad rows 375..383 zeroed -> S1 -= 9)
//   S2 = f_hat . Qsum[label]     (prep-kernel Qsum, per-row in staging)
//   per = log(exp(2*def)+S1-9) - (2*S2 + 2*def)/126
//   out = sum(mask*per)/B

#define D       128
#define NQ      375
#define NQP     384          // padded
#define QS      125
#define MTILE   64
#define CHUNK   64
#define NCHUNKS 6
#define RSTRIDE 272          // bytes per LDS row: 256 data + 16 pad
#define TWO_T   2.0f         // 1/TEMP... exp(dot/T) = exp(2*dot)

typedef __attribute__((ext_vector_type(8))) short short8;
typedef __attribute__((ext_vector_type(4))) float f32x4;

static __device__ __forceinline__ unsigned f2bf2(float lo, float hi) {
    // two floats -> packed bf16x2, round-to-nearest-even
    unsigned a = __float_as_uint(lo), b = __float_as_uint(hi);
    a = (a + 0x7fff + ((a >> 16) & 1)) >> 16;
    b = (b + 0x7fff + ((b >> 16) & 1)) >> 16;
    return (a & 0xffff) | (b << 16);
}

// ---- prep 1: queue fp32 -> bf16, zero-pad to 384 rows ----
__global__ void pgc_prep_qbf(const float* __restrict__ queue,
                             unsigned short* __restrict__ qbf)
{
    int idx = blockIdx.x * 256 + threadIdx.x;      // over 384*128
    if (idx >= NQP * D) return;
    int row = idx >> 7;
    float v = (row < NQ) ? queue[idx] : 0.f;
    unsigned u = __float_as_uint(v);
    qbf[idx] = (unsigned short)((u + 0x7fff + ((u >> 16) & 1)) >> 16);
}

// ---- prep 2: Qsum[c][d] = sum over class block of normalized queue ----
__global__ void pgc_prep_qsum(const float* __restrict__ queue,
                              float* __restrict__ qsum)
{
    int c = blockIdx.x;          // 0..2
    int d = threadIdx.x;         // 0..127
    float s = 0.f;
    const float* p = queue + (long)c * QS * D + d;
    for (int r = 0; r < QS; ++r) s += p[r * D];
    qsum[c * D + d] = s;
}

// ---- main ----
__global__ __launch_bounds__(256, 4) void pgc_main(
    const float* __restrict__ act,
    const float* __restrict__ ema,
    const float* __restrict__ plab,
    const float* __restrict__ mask,
    const unsigned short* __restrict__ qbf,
    const float* __restrict__ qsum,
    float* __restrict__ out,
    int B, float invB)
{
    __shared__ unsigned char f_lds[MTILE * RSTRIDE];
    __shared__ unsigned char q_lds[CHUNK * RSTRIDE];
    __shared__ float s_def2[MTILE];   // 2*dot(f_hat, ef_hat)
    __shared__ float s_s2[MTILE];     // f_hat . Qsum[label]
    __shared__ float s_mask[MTILE];
    __shared__ float s_red[4];

    const int tid = threadIdx.x;
    const long block_m0 = (long)blockIdx.x * MTILE;

    // ======== stage f tile: normalize, scale by 2, bf16, per-row stats ========
    {
        const int row = tid >> 2;       // 0..63
        const int seg = tid & 3;        // 32 floats each
        const long grow = block_m0 + row;
        const bool valid = grow < (long)B;

        float4 av[8];
        float ssa = 0.f;
        const float* arow = act + grow * D + seg * 32;
        #pragma unroll
        for (int it = 0; it < 8; ++it) {
            float4 v = valid ? *(const float4*)(arow + it * 4)
                             : make_float4(0.f, 0.f, 0.f, 0.f);
            av[it] = v;
            ssa += v.x*v.x + v.y*v.y + v.z*v.z + v.w*v.w;
        }
        float sse = 0.f, dae = 0.f;
        const float* erow = ema + grow * D + seg * 32;
        #pragma unroll
        for (int it = 0; it < 8; ++it) {
            float4 e = valid ? *(const float4*)(erow + it * 4)
                             : make_float4(0.f, 0.f, 0.f, 0.f);
            sse += e.x*e.x + e.y*e.y + e.z*e.z + e.w*e.w;
            dae += av[it].x*e.x + av[it].y*e.y + av[it].z*e.z + av[it].w*e.w;
        }
        float dq0 = 0.f, dq1 = 0.f, dq2 = 0.f;
        const float* q0 = qsum + seg * 32;
        #pragma unroll
        for (int it = 0; it < 8; ++it) {
            float4 u0 = *(const float4*)(q0 + it * 4);
            float4 u1 = *(const float4*)(q0 + D + it * 4);
            float4 u2 = *(const float4*)(q0 + 2 * D + it * 4);
            dq0 += av[it].x*u0.x + av[it].y*u0.y + av[it].z*u0.z + av[it].w*u0.w;
            dq1 += av[it].x*u1.x + av[it].y*u1.y + av[it].z*u1.z + av[it].w*u1.w;
            dq2 += av[it].x*u2.x + av[it].y*u2.y + av[it].z*u2.z + av[it].w*u2.w;
        }
        // reduce across the 4 lanes of this row
        ssa += __shfl_xor(ssa, 1); ssa += __shfl_xor(ssa, 2);
        sse += __shfl_xor(sse, 1); sse += __shfl_xor(sse, 2);
        dae += __shfl_xor(dae, 1); dae += __shfl_xor(dae, 2);
        dq0 += __shfl_xor(dq0, 1); dq0 += __shfl_xor(dq0, 2);
        dq1 += __shfl_xor(dq1, 1); dq1 += __shfl_xor(dq1, 2);
        dq2 += __shfl_xor(dq2, 1); dq2 += __shfl_xor(dq2, 2);

        const float inva = 1.0f / fmaxf(sqrtf(ssa), 1e-12f);
        const float inve = 1.0f / fmaxf(sqrtf(sse), 1e-12f);

        // write g = 2*inva*act as bf16 (32 values = 4x 16B)
        const float gs = TWO_T * inva;
        unsigned char* dst = &f_lds[row * RSTRIDE + seg * 64];
        #pragma unroll
        for (int q = 0; q < 4; ++q) {
            float4 v0 = av[q * 2], v1 = av[q * 2 + 1];
            uint4 wv;
            wv.x = f2bf2(gs * v0.x, gs * v0.y);
            wv.y = f2bf2(gs * v0.z, gs * v0.w);
            wv.z = f2bf2(gs * v1.x, gs * v1.y);
            wv.w = f2bf2(gs * v1.z, gs * v1.w);
            *(uint4*)(dst + q * 16) = wv;
        }

        if (seg == 0) s_def2[row] = TWO_T * dae * inva * inve;
        if (seg == 1) s_mask[row] = valid ? mask[grow] : 0.f;
        if (seg == 2) {
            int lb = 0;
            float d0 = dq0, d1 = dq1, d2 = dq2;
            if (valid) {
                const float* p = plab + grow * 3;
                float p0 = p[0], p1 = p[1], p2 = p[2];
                float bst = p0;
                if (p1 > bst) { bst = p1; lb = 1; }
                if (p2 > bst) { lb = 2; }
            }
            float sel = (lb == 0) ? d0 : ((lb == 1) ? d1 : d2);
            s_s2[row] = sel * inva;
        }
    }
    __syncthreads();

    // ======== per-wave fragment setup ========
    const int w  = tid >> 6;
    const int l  = tid & 63;
    const int lr = l & 15;      // row-in-tile / col-in-tile
    const int lg = l >> 4;      // k-group

    short8 afr[4];
    #pragma unroll
    for (int ks = 0; ks < 4; ++ks)
        afr[ks] = *(const short8*)&f_lds[(w * 16 + lr) * RSTRIDE + ks * 64 + lg * 16];

    float S1[4] = {0.f, 0.f, 0.f, 0.f};
    const uint4* qbf4 = (const uint4*)qbf;

    for (int c0 = 0; c0 < NCHUNKS; ++c0) {
        // stage queue chunk (reg-staged, 64 rows x 256B)
        uint4 qv[4];
        #pragma unroll
        for (int it = 0; it < 4; ++it)
            qv[it] = qbf4[c0 * 1024 + it * 256 + tid];
        __syncthreads();   // previous chunk's reads done
        #pragma unroll
        for (int it = 0; it < 4; ++it) {
            int idx = it * 256 + tid;
            *(uint4*)&q_lds[(idx >> 4) * RSTRIDE + (idx & 15) * 16] = qv[it];
        }
        __syncthreads();

        #pragma unroll
        for (int nt = 0; nt < 4; ++nt) {
            f32x4 acc = {0.f, 0.f, 0.f, 0.f};
            #pragma unroll
            for (int ks = 0; ks < 4; ++ks) {
                short8 bfr = *(const short8*)&q_lds[(nt * 16 + lr) * RSTRIDE + ks * 64 + lg * 16];
                acc = __builtin_amdgcn_mfma_f32_16x16x32_bf16(afr[ks], bfr, acc, 0, 0, 0);
            }
            #pragma unroll
            for (int r = 0; r < 4; ++r)
                S1[r] += __expf(acc[r]);
        }
    }

    // reduce S1 across the 16 queue-col lanes
    #pragma unroll
    for (int r = 0; r < 4; ++r) {
        S1[r] += __shfl_xor(S1[r], 1);
        S1[r] += __shfl_xor(S1[r], 2);
        S1[r] += __shfl_xor(S1[r], 4);
        S1[r] += __shfl_xor(S1[r], 8);
    }

    float contrib = 0.f;
    if (lr == 0) {
        #pragma unroll
        for (int r = 0; r < 4; ++r) {
            const int m = w * 16 + lg * 4 + r;
            const float def2 = s_def2[m];
            const float denom = __expf(def2) + S1[r] - 9.0f;   // remove pad rows
            const float per = __logf(denom)
                              - (TWO_T * s_s2[m] + def2) * (1.0f / 126.0f);
            contrib += s_mask[m] * per;
        }
    }
    #pragma unroll
    for (int sh = 1; sh <= 32; sh <<= 1) contrib += __shfl_xor(contrib, sh);

    if (l == 0) s_red[w] = contrib;
    __syncthreads();
    if (tid == 0) {
        float t = s_red[0] + s_red[1] + s_red[2] + s_red[3];
        atomicAdd(out, t * invB);
    }
}

extern "C" void kernel_launch(void* const* d_in, const int* in_sizes, int n_in,
                              void* d_out, int out_size, void* d_ws, size_t ws_size,
                              hipStream_t stream)
{
    const float* act   = (const float*)d_in[0];
    const float* ema   = (const float*)d_in[1];
    const float* plab  = (const float*)d_in[2];
    const float* mask  = (const float*)d_in[3];
    const float* queue = (const float*)d_in[4];
    float* out = (float*)d_out;

    const int B = in_sizes[0] / D;

    unsigned short* qbf  = (unsigned short*)d_ws;                 // 384*128*2 = 98304 B
    float*          qsum = (float*)((char*)d_ws + NQP * D * 2);   // 3*128*4   = 1536 B

    hipMemsetAsync(out, 0, sizeof(float), stream);

    pgc_prep_qbf<<<(NQP * D + 255) / 256, 256, 0, stream>>>(queue, qbf);
    pgc_prep_qsum<<<3, D, 0, stream>>>(queue, qsum);

    const int grid = (B + MTILE - 1) / MTILE;
    pgc_main<<<grid, 256, 0, stream>>>(act, ema, plab, mask, qbf, qsum, out,
                                       B, 1.0f / (float)B);
}

// Round 5
// 59.645 us; speedup vs baseline: 4.2829x; 2.0616x over previous
//
#include <hip/hip_runtime.h>
#include <math.h>

// PseudoGroupContrast — queue-resident single-pass design.
//
//   One 1024-thread block per CU (grid = B/512). Per block:
//     - full queue (384x128, zero-padded) staged fp32->bf16 into LDS ONCE
//     - each wave owns 32 rows; A-fragments (g=2*f_hat, bf16) built directly
//       in registers from global (f never touches LDS)
//     - ONE barrier, then barrier-free loop over 24 B-tiles:
//         4x ds_read_b128 -> 8 MFMA (2 row-groups share B-frags) -> 8 exp
//     - S1 = sum exp(2*dot) (pad rows give exp(0)=1 -> subtract 9)
//       S2 = sum of acc over this row's label block, via predicated add
//   per = log(exp(def2)+S1-9) - (S2 + def2)/126,  def2 = 2*dot(f_hat,ef_hat)
//   out = sum(mask*per)/B

#define D        128
#define NQ       375
#define NQP      384
#define QS       125
#define RPB      512          // rows per block (16 waves x 32)
#define RSTRIDE  272          // LDS bytes per queue row (256 data + 16 pad)
#define NTILES   24           // 384/16
#define INV126   (1.0f/126.0f)

typedef __attribute__((ext_vector_type(8))) short short8;
typedef __attribute__((ext_vector_type(4))) float f32x4;

static __device__ __forceinline__ unsigned f2bf2(float lo, float hi) {
    // two floats -> packed bf16x2, round-to-nearest-even
    unsigned a = __float_as_uint(lo), b = __float_as_uint(hi);
    a = (a + 0x7fff + ((a >> 16) & 1)) >> 16;
    b = (b + 0x7fff + ((b >> 16) & 1)) >> 16;
    return (a & 0xffff) | (b << 16);
}

static __device__ __forceinline__ short8 pack8(float gs, float4 a, float4 b) {
    union { unsigned u[4]; short8 s; } r;
    r.u[0] = f2bf2(gs * a.x, gs * a.y);
    r.u[1] = f2bf2(gs * a.z, gs * a.w);
    r.u[2] = f2bf2(gs * b.x, gs * b.y);
    r.u[3] = f2bf2(gs * b.z, gs * b.w);
    return r.s;
}

__global__ __launch_bounds__(1024, 4) void pgc_main(
    const float* __restrict__ act,
    const float* __restrict__ ema,
    const float* __restrict__ plab,
    const float* __restrict__ mask,
    const float* __restrict__ queue,
    float* __restrict__ out,
    int B, float invB)
{
    __shared__ unsigned char q_lds[NQP * RSTRIDE];   // 104448 B
    __shared__ float s_def2[RPB];
    __shared__ float s_mask[RPB];
    __shared__ int   s_lab[RPB];
    __shared__ float s_red[16];

    const int tid = threadIdx.x;
    const int w   = tid >> 6;
    const int l   = tid & 63;
    const int lr  = l & 15;       // A/B fragment row, C col
    const int seg = l >> 4;       // k-segment / C row group
    const long blockBase = (long)blockIdx.x * RPB;

    // ======== stage queue -> LDS bf16 (once; rows >= NQ zeroed) ========
    #pragma unroll
    for (int i = 0; i < 6; ++i) {
        int idx = i * 1024 + tid;            // 6144 chunks of 16 B
        int row = idx >> 4, ch = idx & 15;
        float4 a = make_float4(0.f, 0.f, 0.f, 0.f);
        float4 b = make_float4(0.f, 0.f, 0.f, 0.f);
        if (row < NQ) {
            const float* qp = queue + row * D + ch * 8;
            a = *(const float4*)qp;
            b = *(const float4*)(qp + 4);
        }
        uint4 wv;
        wv.x = f2bf2(a.x, a.y); wv.y = f2bf2(a.z, a.w);
        wv.z = f2bf2(b.x, b.y); wv.w = f2bf2(b.z, b.w);
        *(uint4*)&q_lds[row * RSTRIDE + ch * 16] = wv;
    }

    // ======== build A-fragments in registers (2 groups of 16 rows) ========
    short8 af[2][4];
    #pragma unroll
    for (int g = 0; g < 2; ++g) {
        const long grow  = blockBase + w * 32 + g * 16 + lr;
        const bool valid = grow < (long)B;
        const float* ap = act + grow * D + seg * 8;
        const float* ep = ema + grow * D + seg * 8;

        float4 av[8];
        float ssa = 0.f;
        #pragma unroll
        for (int ks = 0; ks < 4; ++ks) {
            float4 a0 = valid ? *(const float4*)(ap + ks * 32)
                              : make_float4(0.f, 0.f, 0.f, 0.f);
            float4 a1 = valid ? *(const float4*)(ap + ks * 32 + 4)
                              : make_float4(0.f, 0.f, 0.f, 0.f);
            av[2 * ks]     = a0;
            av[2 * ks + 1] = a1;
            ssa += a0.x*a0.x + a0.y*a0.y + a0.z*a0.z + a0.w*a0.w;
            ssa += a1.x*a1.x + a1.y*a1.y + a1.z*a1.z + a1.w*a1.w;
        }
        float sse = 0.f, dae = 0.f;
        #pragma unroll
        for (int ks = 0; ks < 4; ++ks) {
            float4 e0 = valid ? *(const float4*)(ep + ks * 32)
                              : make_float4(0.f, 0.f, 0.f, 0.f);
            float4 e1 = valid ? *(const float4*)(ep + ks * 32 + 4)
                              : make_float4(0.f, 0.f, 0.f, 0.f);
            float4 a0 = av[2 * ks], a1 = av[2 * ks + 1];
            sse += e0.x*e0.x + e0.y*e0.y + e0.z*e0.z + e0.w*e0.w;
            sse += e1.x*e1.x + e1.y*e1.y + e1.z*e1.z + e1.w*e1.w;
            dae += a0.x*e0.x + a0.y*e0.y + a0.z*e0.z + a0.w*e0.w;
            dae += a1.x*e1.x + a1.y*e1.y + a1.z*e1.z + a1.w*e1.w;
        }
        // reduce partials across the 4 k-segment lanes of this row
        ssa += __shfl_xor(ssa, 16); ssa += __shfl_xor(ssa, 32);
        sse += __shfl_xor(sse, 16); sse += __shfl_xor(sse, 32);
        dae += __shfl_xor(dae, 16); dae += __shfl_xor(dae, 32);

        const float inva = 1.0f / fmaxf(sqrtf(ssa), 1e-12f);
        const float inve = 1.0f / fmaxf(sqrtf(sse), 1e-12f);
        const float gs   = 2.0f * inva;     // fold 1/T and norm into A

        #pragma unroll
        for (int ks = 0; ks < 4; ++ks)
            af[g][ks] = pack8(gs, av[2 * ks], av[2 * ks + 1]);

        if (seg == 0) {
            const int rloc = w * 32 + g * 16 + lr;
            s_def2[rloc] = 2.0f * dae * inva * inve;
            s_mask[rloc] = valid ? mask[grow] : 0.f;
            int lb = 0;
            if (valid) {
                const float* p = plab + grow * 3;
                float p0 = p[0], p1 = p[1], p2 = p[2];
                float bst = p0;
                if (p1 > bst) { bst = p1; lb = 1; }   // first-max tie-break
                if (p2 > bst) { lb = 2; }
            }
            s_lab[rloc] = lb;
        }
    }
    __syncthreads();   // q_lds + s_* ready; ONLY barrier before epilogue

    // preload this lane's label-block starts (C rows: seg*4 + r)
    int lo8[2][4];
    #pragma unroll
    for (int g = 0; g < 2; ++g)
        #pragma unroll
        for (int r = 0; r < 4; ++r)
            lo8[g][r] = s_lab[w * 32 + g * 16 + seg * 4 + r] * QS;

    float S1[2][4] = {{0.f,0.f,0.f,0.f},{0.f,0.f,0.f,0.f}};
    float S2[2][4] = {{0.f,0.f,0.f,0.f},{0.f,0.f,0.f,0.f}};

    #pragma unroll 4
    for (int nt = 0; nt < NTILES; ++nt) {
        const unsigned char* bp = &q_lds[(nt * 16 + lr) * RSTRIDE + seg * 16];
        short8 b0 = *(const short8*)(bp);
        short8 b1 = *(const short8*)(bp + 64);
        short8 b2 = *(const short8*)(bp + 128);
        short8 b3 = *(const short8*)(bp + 192);
        const int col = nt * 16 + lr;
        #pragma unroll
        for (int g = 0; g < 2; ++g) {
            f32x4 acc = {0.f, 0.f, 0.f, 0.f};
            acc = __builtin_amdgcn_mfma_f32_16x16x32_bf16(af[g][0], b0, acc, 0, 0, 0);
            acc = __builtin_amdgcn_mfma_f32_16x16x32_bf16(af[g][1], b1, acc, 0, 0, 0);
            acc = __builtin_amdgcn_mfma_f32_16x16x32_bf16(af[g][2], b2, acc, 0, 0, 0);
            acc = __builtin_amdgcn_mfma_f32_16x16x32_bf16(af[g][3], b3, acc, 0, 0, 0);
            #pragma unroll
            for (int r = 0; r < 4; ++r) {
                S1[g][r] += __expf(acc[r]);
                if ((unsigned)(col - lo8[g][r]) < (unsigned)QS)
                    S2[g][r] += acc[r];          // acc = 2*dot already
            }
        }
    }

    // reduce S1/S2 over the 16 column lanes
    #pragma unroll
    for (int g = 0; g < 2; ++g)
        #pragma unroll
        for (int r = 0; r < 4; ++r) {
            S1[g][r] += __shfl_xor(S1[g][r], 1);
            S1[g][r] += __shfl_xor(S1[g][r], 2);
            S1[g][r] += __shfl_xor(S1[g][r], 4);
            S1[g][r] += __shfl_xor(S1[g][r], 8);
            S2[g][r] += __shfl_xor(S2[g][r], 1);
            S2[g][r] += __shfl_xor(S2[g][r], 2);
            S2[g][r] += __shfl_xor(S2[g][r], 4);
            S2[g][r] += __shfl_xor(S2[g][r], 8);
        }

    float contrib = 0.f;
    if (lr == 0) {
        #pragma unroll
        for (int g = 0; g < 2; ++g)
            #pragma unroll
            for (int r = 0; r < 4; ++r) {
                const int m = w * 32 + g * 16 + seg * 4 + r;
                const float def2  = s_def2[m];
                const float denom = __expf(def2) + S1[g][r] - 9.0f;  // drop pads
                const float per   = __logf(denom) - (S2[g][r] + def2) * INV126;
                contrib += s_mask[m] * per;
            }
    }
    contrib += __shfl_xor(contrib, 16);
    contrib += __shfl_xor(contrib, 32);
    if (l == 0) s_red[w] = contrib;
    __syncthreads();
    if (w == 0) {
        float v = (l < 16) ? s_red[l] : 0.f;
        v += __shfl_xor(v, 1); v += __shfl_xor(v, 2);
        v += __shfl_xor(v, 4); v += __shfl_xor(v, 8);
        if (l == 0) atomicAdd(out, v * invB);
    }
}

extern "C" void kernel_launch(void* const* d_in, const int* in_sizes, int n_in,
                              void* d_out, int out_size, void* d_ws, size_t ws_size,
                              hipStream_t stream)
{
    const float* act   = (const float*)d_in[0];
    const float* ema   = (const float*)d_in[1];
    const float* plab  = (const float*)d_in[2];
    const float* mask  = (const float*)d_in[3];
    const float* queue = (const float*)d_in[4];
    float* out = (float*)d_out;

    const int B = in_sizes[0] / D;

    hipMemsetAsync(out, 0, sizeof(float), stream);

    const int grid = (B + RPB - 1) / RPB;   // 256 for B=131072 -> 1 block/CU
    pgc_main<<<grid, 1024, 0, stream>>>(act, ema, plab, mask, queue, out,
                                        B, 1.0f / (float)B);
}

// Round 7
// 57.297 us; speedup vs baseline: 4.4585x; 1.0410x over previous
//
#include <hip/hip_runtime.h>
#include <math.h>

// PseudoGroupContrast — queue-resident + async glds staging pipeline.
//
//   grid = B/512, block = 1024 (16 waves), 1 block/CU.
//   Pipeline (per wave, barrier-free): 8 stages x 8 rows (4 act + 4 ema),
//   double-buffered 64KB chunks, global_load_lds w=16, counted vmcnt(4).
//   LDS dest linear; global SOURCE pre-swizzled (granule ^ row) so the
//   strided fragment ds_read_b128s are bank-spread (m173 pattern).
//   Then queue (384x128, zero-pad) overlays the stage region as bf16,
//   RSTRIDE=272 (2-way = free), and the barrier-free MFMA loop runs.
//
//   af = bf16(2*inva*act) -> MFMA acc = 2*dot
//   S1 = sum exp(2*dot) (9 pad rows -> -9);  S2 = label-block sum of acc
//   def2 = 2*dot(f_hat,ef_hat) (from bf16 af x fp32 ema)
//   per = log(exp(def2)+S1-9) - (S2+def2)/126;  out = sum(mask*per)/B

#define D        128
#define NQ       375
#define NQP      384
#define QS       125
#define RPB      512          // rows per block (16 waves x 32)
#define RSTRIDE  272          // queue LDS row stride (bytes)
#define NTILES   24
#define INV126   (1.0f/126.0f)
#define STG      65536        // staging chunk bytes (16 waves x 8 rows x 512B)

typedef __attribute__((ext_vector_type(8))) short short8;
typedef __attribute__((ext_vector_type(4))) float f32x4;

static __device__ __forceinline__ unsigned f2bf2(float lo, float hi) {
    unsigned a = __float_as_uint(lo), b = __float_as_uint(hi);
    a = (a + 0x7fff + ((a >> 16) & 1)) >> 16;
    b = (b + 0x7fff + ((b >> 16) & 1)) >> 16;
    return (a & 0xffff) | (b << 16);
}

static __device__ __forceinline__ short8 pack8(float gs, float4 a, float4 b) {
    union { unsigned u[4]; short8 s; } r;
    r.u[0] = f2bf2(gs * a.x, gs * a.y);
    r.u[1] = f2bf2(gs * a.z, gs * a.w);
    r.u[2] = f2bf2(gs * b.x, gs * b.y);
    r.u[3] = f2bf2(gs * b.z, gs * b.w);
    return r.s;
}

static __device__ __forceinline__ float bf2f(short s) {
    return __uint_as_float(((unsigned)(unsigned short)s) << 16);
}

static __device__ __forceinline__ void glds16(const void* g, void* l) {
    __builtin_amdgcn_global_load_lds(
        (const __attribute__((address_space(1))) void*)g,
        (__attribute__((address_space(3))) void*)l, 16, 0, 0);
}

#define WAITV(n) do { asm volatile("s_waitcnt vmcnt(" #n ")" ::: "memory"); \
                      __builtin_amdgcn_sched_barrier(0); } while (0)
#define WAITL()  do { asm volatile("s_waitcnt lgkmcnt(0)" ::: "memory"); \
                      __builtin_amdgcn_sched_barrier(0); } while (0)

__global__ __launch_bounds__(1024, 4) void pgc_main(
    const float* __restrict__ act,
    const float* __restrict__ ema,
    const float* __restrict__ plab,
    const float* __restrict__ mask,
    const float* __restrict__ queue,
    float* __restrict__ out,
    int B, float invB)
{
    __shared__ unsigned char stage[2 * STG];   // staging; queue overlays later
    __shared__ float s_def2[RPB];
    __shared__ float s_mask[RPB];
    __shared__ int   s_lab[RPB];
    __shared__ float s_red[16];

    const int tid = threadIdx.x;
    const int w   = tid >> 6;
    const int l   = tid & 63;
    const int lr  = l & 15;
    const int seg = l >> 4;
    const long blockBase = (long)blockIdx.x * RPB;

    // ---- per-row mask/label (before pipeline so vmcnt counting is clean) ----
    if (tid < RPB) {
        long grow = blockBase + tid;
        bool valid = grow < (long)B;
        long g2 = valid ? grow : (long)B - 1;
        float mk = valid ? mask[g2] : 0.f;
        const float* p = plab + g2 * 3;
        float p0 = p[0], p1 = p[1], p2 = p[2];
        int lb = 0; float bst = p0;
        if (p1 > bst) { bst = p1; lb = 1; }    // first-max tie-break = argmax
        if (p2 > bst) { lb = 2; }
        s_mask[tid] = mk;
        s_lab[tid]  = lb;
    }
    asm volatile("s_waitcnt vmcnt(0)" ::: "memory");
    __builtin_amdgcn_sched_barrier(0);

    short8 af[2][4];

    // ---- stage issue: 4 glds x 1KB; rows [p*8, p*8+8) of act/ema ----
    auto issue = [&](int s) {
        const float* arr = (s < 4) ? act : ema;
        const int p = s & 3;
        unsigned char* dst = &stage[(s & 1) * STG + w * 4096];
        const long rowbase = blockBase + (long)w * 32 + p * 8;
        #pragma unroll
        for (int i = 0; i < 4; ++i) {
            int rr = 2 * i + (l >> 5);
            long grow = rowbase + rr;
            if (grow >= (long)B) grow = (long)B - 1;     // clamp (masked later)
            const float* src = arr + grow * D + (((l & 31) ^ rr) << 2);
            glds16(src, dst + i * 1024);
        }
    };

    // ---- act consume: norms + pack bf16 fragments (half the lanes) ----
    auto consume_act = [&](int s) {
        const int p = s, g = p >> 1;
        if ((lr >> 3) == (p & 1)) {
            const int rr = lr & 7;
            const unsigned char* base = &stage[(s & 1) * STG + w * 4096 + rr * 512];
            float4 f[8];
            #pragma unroll
            for (int ks = 0; ks < 4; ++ks)
                #pragma unroll
                for (int sub = 0; sub < 2; ++sub) {
                    int j = seg * 2 + sub + ks * 8;
                    f[ks * 2 + sub] = *(const float4*)(base + ((j ^ rr) << 4));
                }
            float ssa = 0.f;
            #pragma unroll
            for (int i = 0; i < 8; ++i)
                ssa += f[i].x*f[i].x + f[i].y*f[i].y + f[i].z*f[i].z + f[i].w*f[i].w;
            ssa += __shfl_xor(ssa, 16); ssa += __shfl_xor(ssa, 32);
            const float inva = 1.0f / fmaxf(sqrtf(ssa), 1e-12f);
            const float gs = 2.0f * inva;
            #pragma unroll
            for (int ks = 0; ks < 4; ++ks)
                af[g][ks] = pack8(gs, f[ks * 2], f[ks * 2 + 1]);
        }
    };

    // ---- ema consume: sse + dae (vs bf16 af) -> def2 ----
    auto consume_ema = [&](int s) {
        const int p = s - 4, g = p >> 1;
        if ((lr >> 3) == (p & 1)) {
            const int rr = lr & 7;
            const unsigned char* base = &stage[(s & 1) * STG + w * 4096 + rr * 512];
            float4 e[8];
            #pragma unroll
            for (int ks = 0; ks < 4; ++ks)
                #pragma unroll
                for (int sub = 0; sub < 2; ++sub) {
                    int j = seg * 2 + sub + ks * 8;
                    e[ks * 2 + sub] = *(const float4*)(base + ((j ^ rr) << 4));
                }
            float sse = 0.f, dae = 0.f;
            #pragma unroll
            for (int ks = 0; ks < 4; ++ks) {
                short8 a = af[g][ks];
                float4 e0 = e[ks * 2], e1 = e[ks * 2 + 1];
                sse += e0.x*e0.x + e0.y*e0.y + e0.z*e0.z + e0.w*e0.w;
                sse += e1.x*e1.x + e1.y*e1.y + e1.z*e1.z + e1.w*e1.w;
                dae += bf2f(a[0])*e0.x + bf2f(a[1])*e0.y + bf2f(a[2])*e0.z + bf2f(a[3])*e0.w;
                dae += bf2f(a[4])*e1.x + bf2f(a[5])*e1.y + bf2f(a[6])*e1.z + bf2f(a[7])*e1.w;
            }
            sse += __shfl_xor(sse, 16); sse += __shfl_xor(sse, 32);
            dae += __shfl_xor(dae, 16); dae += __shfl_xor(dae, 32);
            const float inve = 1.0f / fmaxf(sqrtf(sse), 1e-12f);
            if (seg == 0)
                s_def2[w * 32 + p * 8 + rr] = dae * inve;   // dae has 2*inva folded
        }
    };

    // ---- the 8-stage pipeline (per-wave, barrier-free, counted vmcnt) ----
    issue(0); issue(1);
    WAITV(4); consume_act(0); WAITL(); issue(2);
    WAITV(4); consume_act(1); WAITL(); issue(3);
    WAITV(4); consume_act(2); WAITL(); issue(4);
    WAITV(4); consume_act(3); WAITL(); issue(5);
    WAITV(4); consume_ema(4); WAITL(); issue(6);
    WAITV(4); consume_ema(5); WAITL(); issue(7);
    WAITV(4); consume_ema(6);
    WAITV(0); consume_ema(7);

    __syncthreads();   // all waves done with stage region

    // ---- queue -> LDS bf16 (overlays stage region), RSTRIDE=272 ----
    #pragma unroll
    for (int i = 0; i < 6; ++i) {
        int idx = i * 1024 + tid;            // 6144 chunks of 16B (bf16 row=256B)
        int row = idx >> 4, ch = idx & 15;
        float4 a = make_float4(0.f, 0.f, 0.f, 0.f);
        float4 b = make_float4(0.f, 0.f, 0.f, 0.f);
        if (row < NQ) {
            const float* qp = queue + row * D + ch * 8;
            a = *(const float4*)qp;
            b = *(const float4*)(qp + 4);
        }
        uint4 wv;
        wv.x = f2bf2(a.x, a.y); wv.y = f2bf2(a.z, a.w);
        wv.z = f2bf2(b.x, b.y); wv.w = f2bf2(b.z, b.w);
        *(uint4*)&stage[row * RSTRIDE + ch * 16] = wv;
    }
    __syncthreads();

    // ---- label-block starts for this lane's C rows ----
    int lo8[2][4];
    #pragma unroll
    for (int g = 0; g < 2; ++g)
        #pragma unroll
        for (int r = 0; r < 4; ++r)
            lo8[g][r] = s_lab[w * 32 + g * 16 + seg * 4 + r] * QS;

    float S1[2][4] = {{0.f,0.f,0.f,0.f},{0.f,0.f,0.f,0.f}};
    float S2[2][4] = {{0.f,0.f,0.f,0.f},{0.f,0.f,0.f,0.f}};

    #pragma unroll 4
    for (int nt = 0; nt < NTILES; ++nt) {
        const unsigned char* bp = &stage[(nt * 16 + lr) * RSTRIDE + seg * 16];
        short8 b0 = *(const short8*)(bp);
        short8 b1 = *(const short8*)(bp + 64);
        short8 b2 = *(const short8*)(bp + 128);
        short8 b3 = *(const short8*)(bp + 192);
        const int col = nt * 16 + lr;
        #pragma unroll
        for (int g = 0; g < 2; ++g) {
            f32x4 acc = {0.f, 0.f, 0.f, 0.f};
            acc = __builtin_amdgcn_mfma_f32_16x16x32_bf16(af[g][0], b0, acc, 0, 0, 0);
            acc = __builtin_amdgcn_mfma_f32_16x16x32_bf16(af[g][1], b1, acc, 0, 0, 0);
            acc = __builtin_amdgcn_mfma_f32_16x16x32_bf16(af[g][2], b2, acc, 0, 0, 0);
            acc = __builtin_amdgcn_mfma_f32_16x16x32_bf16(af[g][3], b3, acc, 0, 0, 0);
            #pragma unroll
            for (int r = 0; r < 4; ++r) {
                S1[g][r] += __expf(acc[r]);
                if ((unsigned)(col - lo8[g][r]) < (unsigned)QS)
                    S2[g][r] += acc[r];
            }
        }
    }

    // ---- reduce over the 16 column lanes ----
    #pragma unroll
    for (int g = 0; g < 2; ++g)
        #pragma unroll
        for (int r = 0; r < 4; ++r) {
            S1[g][r] += __shfl_xor(S1[g][r], 1);
            S1[g][r] += __shfl_xor(S1[g][r], 2);
            S1[g][r] += __shfl_xor(S1[g][r], 4);
            S1[g][r] += __shfl_xor(S1[g][r], 8);
            S2[g][r] += __shfl_xor(S2[g][r], 1);
            S2[g][r] += __shfl_xor(S2[g][r], 2);
            S2[g][r] += __shfl_xor(S2[g][r], 4);
            S2[g][r] += __shfl_xor(S2[g][r], 8);
        }

    float contrib = 0.f;
    if (lr == 0) {
        #pragma unroll
        for (int g = 0; g < 2; ++g)
            #pragma unroll
            for (int r = 0; r < 4; ++r) {
                const int m = w * 32 + g * 16 + seg * 4 + r;
                const float def2  = s_def2[m];
                const float denom = __expf(def2) + S1[g][r] - 9.0f;
                const float per   = __logf(denom) - (S2[g][r] + def2) * INV126;
                contrib += s_mask[m] * per;
            }
    }
    contrib += __shfl_xor(contrib, 16);
    contrib += __shfl_xor(contrib, 32);
    if (l == 0) s_red[w] = contrib;
    __syncthreads();
    if (w == 0) {
        float v = (l < 16) ? s_red[l] : 0.f;
        v += __shfl_xor(v, 1); v += __shfl_xor(v, 2);
        v += __shfl_xor(v, 4); v += __shfl_xor(v, 8);
        if (l == 0) atomicAdd(out, v * invB);
    }
}

extern "C" void kernel_launch(void* const* d_in, const int* in_sizes, int n_in,
                              void* d_out, int out_size, void* d_ws, size_t ws_size,
                              hipStream_t stream)
{
    const float* act   = (const float*)d_in[0];
    const float* ema   = (const float*)d_in[1];
    const float* plab  = (const float*)d_in[2];
    const float* mask  = (const float*)d_in[3];
    const float* queue = (const float*)d_in[4];
    float* out = (float*)d_out;

    const int B = in_sizes[0] / D;

    hipMemsetAsync(out, 0, sizeof(float), stream);

    const int grid = (B + RPB - 1) / RPB;   // 256 for B=131072 -> 1 block/CU
    pgc_main<<<grid, 1024, 0, stream>>>(act, ema, plab, mask, queue, out,
                                        B, 1.0f / (float)B);
}